// Round 1
// 242.681 us; speedup vs baseline: 1.0344x; 1.0344x over previous
//
#include <hip/hip_runtime.h>
#include <cmath>

// ---------------------------------------------------------------------------
// EquivariantCorrectionHead — round 12: hide load latency + balance waves.
// 5-stage, 4-barrier pipeline per iteration:
//  S1  marshal (staging, t build, qT->qB per-element, ss) [per half-wave]
//      + issue NEXT group's global loads into registers (prefetch)
//  S2  MFMA: h0 (w0), Cvv (w1-2), p5 = W111@qT per k (w3-7)
//  S3a h2 = Cvv.t (dot2) + p5; write h2B [per half-wave]
//  S2b MFMA: aB_j = V110 @ h2_j (w0-4); g = Mr @ h0 (w5, moved from S2)
//  S3c a,g read; final CG + reduce + store [per half-wave]
// In-loop barriers are raw s_barrier + lgkmcnt(0) (NO vmcnt drain) so the
// register prefetch stays in flight across the whole loop body.
// Loop-top B1 is the cross-iteration fence for all block-level buffers.
// aB overlays p5 (dead after S3a); qB overlays raw staging (dead after S1).
// LDS ~81KB -> 2 blocks/CU (critical budget).
// ---------------------------------------------------------------------------

#define DEVINL static __device__ __forceinline__

typedef _Float16 half2_t __attribute__((ext_vector_type(2)));
typedef _Float16 half8_t __attribute__((ext_vector_type(8)));
typedef float    f32x4_t __attribute__((ext_vector_type(4)));
union H8 { half8_t v; half2_t p[4]; };

// ---- slab offsets in HALVES ----
#define FW0   0        // 12 x 512: A-frags [W000|W110] (2 Mt x 6 Ks, K=192)
#define FWC   6144     // 18 x 256: A-frags wc (quads 0-1 only; K=16, pad in-reg)
#define FMR   10752    // 2 x 512:  A-frags Mr
#define FW111 11776    // 4 x 512:  A-frags W111 (2 Mt x 2 Ks, K=64, p>=45 zero)
#define FV110 13824    // 2 x 512:  A-frags V110 (2 Mt, K=32)
#define SLABH 14848

__device__ __align__(16) _Float16 g_wsh[SLABH];

struct CPack { float v[32]; };

// C222 nonzero superset (exact O(3) parity selection rule)
static constexpr int CIa[32] = {2,2,2,4,2,4,4,4, 2,0,0, 2,1,1, 2,3,3, 4,0,0, 4,1,1, 4,3,3, 0,0,1,1,3,3};
static constexpr int CJa[32] = {2,2,4,2,4,2,4,4, 0,2,0, 1,2,1, 3,2,3, 0,4,0, 1,4,1, 3,4,3, 1,3,0,3,0,1};
static constexpr int CKa[32] = {2,4,2,2,4,4,2,4, 0,0,2, 1,1,2, 3,3,2, 0,0,4, 1,1,4, 3,3,4, 3,1,3,0,1,0};

__host__ __device__ inline void tri_uv(int p, int n, int& u, int& v) {
  int base = 0;
  for (int x = 0; x < n; x++) {
    int c = n - x;
    if (p < base + c) { u = x; v = x + (p - base); return; }
    base += c;
  }
  u = n - 1; v = n - 1;
}

// ---- host analytic C222 (round-4 proven sign) ----
static double h_trE3(const double A[3][3], const double B[3][3], const double C[3][3]) {
  double t = 0.0;
  for (int r = 0; r < 3; r++)
    for (int c = 0; c < 3; c++) {
      double ab = 0.0;
      for (int m = 0; m < 3; m++) ab += A[r][m] * B[m][c];
      t += ab * C[c][r];
    }
  return t;
}
static void computeC(CPack& out) {
  const double s2i = 0.7071067811865475244, s6i = 0.4082482904638630164;
  double E[5][3][3] = {
    {{0, s2i, 0}, {s2i, 0, 0}, {0, 0, 0}},
    {{0, 0, 0}, {0, 0, s2i}, {0, s2i, 0}},
    {{-s6i, 0, 0}, {0, -s6i, 0}, {0, 0, 2.0 * s6i}},
    {{0, 0, s2i}, {0, 0, 0}, {s2i, 0, 0}},
    {{s2i, 0, 0}, {0, -s2i, 0}, {0, 0, 0}}
  };
  double T[125], nrm = 0.0;
  for (int f = 0; f < 125; f++) {
    int i = f / 25, j = (f / 5) % 5, k = f % 5;
    T[f] = h_trE3(E[i], E[j], E[k]) + h_trE3(E[i], E[k], E[j]);
    nrm += T[f] * T[f];
  }
  nrm = std::sqrt(nrm);
  int am = 0; double mx = std::fabs(T[0]);
  for (int q = 1; q < 125; q++) { double v = std::fabs(T[q]); if (v > mx) { mx = v; am = q; } }
  const double scale = ((T[am] < 0.0) ? 1.0 : -1.0) / nrm;
  for (int s = 0; s < 32; s++)
    out.v[s] = (float)(scale * T[(CIa[s] * 5 + CJa[s]) * 5 + CKa[s]]);
}

// ---- device helpers ----
DEVINL float dot2f(half2_t a, half2_t b, float c) {
#if __has_builtin(__builtin_amdgcn_fdot2)
  return __builtin_amdgcn_fdot2(a, b, c, false);
#else
  return fmaf((float)a[0], (float)b[0], fmaf((float)a[1], (float)b[1], c));
#endif
}
DEVINL half2_t pk2(float a, float b) {
  auto r = __builtin_amdgcn_cvt_pkrtz(a, b);
  half2_t o;
  __builtin_memcpy(&o, &r, sizeof(o));
  return o;
}
DEVINL int h2i(half2_t h) { int i; __builtin_memcpy(&i, &h, 4); return i; }
DEVINL half2_t i2h(int i) { half2_t h; __builtin_memcpy(&h, &i, 4); return h; }
DEVINL f32x4_t mfma16(half8_t a, half8_t b, f32x4_t c) {
  return __builtin_amdgcn_mfma_f32_16x16x32_f16(a, b, c, 0, 0, 0);
}
DEVINL void store4h(_Float16* p, f32x4_t d) {
  int2 v;
  v.x = h2i(pk2(d[0], d[1]));
  v.y = h2i(pk2(d[2], d[3]));
  *(int2*)p = v;
}

// In-loop barrier: drain LDS (lgkmcnt) for cross-wave visibility, but do NOT
// drain vmcnt — the cross-iteration global prefetch must stay in flight.
// sched_barrier(0) after s_barrier keeps the compiler from hoisting LDS reads
// above the barrier (rule #18-style pinning); "memory" clobber on the asm
// keeps LDS writes from sinking below it.
DEVINL void bar_lds() {
  asm volatile("s_waitcnt lgkmcnt(0)" ::: "memory");
  __builtin_amdgcn_s_barrier();
  __builtin_amdgcn_sched_barrier(0);
}

// ---------------------------------------------------------------------------
// Setup: pack all weights as MFMA A-fragments (constants folded)
// ---------------------------------------------------------------------------
__global__ void ech_setup(const float* __restrict__ w000, const float* __restrict__ w110,
                          const float* __restrict__ w011, const float* __restrict__ w101,
                          const float* __restrict__ w111, const float* __restrict__ v010,
                          const float* __restrict__ v100, const float* __restrict__ v110) {
  const float c0   = 1.0f / sqrtf(337.0f);
  const float inv5 = 0.44721359549995794f;
  const float c2   = sqrtf(5.0f / 369.0f);
  const float dm   = sqrtf(5.0f / 3072.0f) * inv5;
  int gid = blockIdx.x * blockDim.x + threadIdx.x;
  int gs  = gridDim.x * blockDim.x;

  // FW0: A-frags of combined W[w][p]: p<136 sym-w000(tri16), p<181 sym-w110
  for (int idx = gid; idx < 6144; idx += gs) {
    int j = idx & 7, L = (idx >> 3) & 63, tk = idx >> 9;
    int mt = tk / 6, ks = tk % 6;
    int w = mt * 16 + (L & 15);
    int p = ks * 32 + (L >> 4) * 8 + j;
    float x = 0.0f;
    if (p < 136) {
      int u, v; tri_uv(p, 16, u, v);
      x = c0 * (w000[(u * 16 + v) * 32 + w] + (u != v ? w000[(v * 16 + u) * 32 + w] : 0.0f));
    } else if (p < 181) {
      int u, v; tri_uv(p - 136, 9, u, v);
      x = c0 * inv5 * (w110[(u * 9 + v) * 32 + w] + (u != v ? w110[(v * 9 + u) * 32 + w] : 0.0f));
    }
    g_wsh[FW0 + idx] = (_Float16)x;
  }
  // FWC: A-frags of wc[m=w*9+v][k=u], quads 0-1 only (K=16)
  for (int idx = gid; idx < 4608; idx += gs) {
    int j = idx & 7, L = (idx >> 3) & 31, t = idx >> 8;
    int m = t * 16 + (L & 15);
    int w = m / 9, v = m % 9;
    int u = (L >> 4) * 8 + j;
    g_wsh[FWC + idx] =
        (_Float16)(c2 * inv5 * (w011[(u * 9 + v) * 32 + w] + w101[(v * 16 + u) * 32 + w]));
  }
  // FMR: A-frags of Mr[w][u]
  for (int idx = gid; idx < 1024; idx += gs) {
    int j = idx & 7, L = (idx >> 3) & 63, mt = idx >> 9;
    int w = mt * 16 + (L & 15);
    int u = (L >> 4) * 8 + j;
    g_wsh[FMR + idx] = (_Float16)(dm * (v010[u * 32 + w] + v100[w * 32 + u]));
  }
  // FW111: A-frags (2 Mt x 2 Ks), A[m=w][k=p], p>=45 zero
  for (int idx = gid; idx < 2048; idx += gs) {
    int j = idx & 7, L = (idx >> 3) & 63, t = idx >> 9;
    int mt = t >> 1, ks = t & 1;
    int w = mt * 16 + (L & 15);
    int p = ks * 32 + (L >> 4) * 8 + j;
    float x = 0.0f;
    if (p < 45) { int u, v; tri_uv(p, 9, u, v);
      x = c2 * (w111[(u * 9 + v) * 32 + w] + (u != v ? w111[(v * 9 + u) * 32 + w] : 0.0f)); }
    g_wsh[FW111 + idx] = (_Float16)x;
  }
  // FV110: A-frags (2 Mt), A[m=u][k=v]
  for (int idx = gid; idx < 1024; idx += gs) {
    int j = idx & 7, L = (idx >> 3) & 63, mt = idx >> 9;
    int u = mt * 16 + (L & 15);
    int v = (L >> 4) * 8 + j;
    g_wsh[FV110 + idx] = (_Float16)v110[u * 32 + v];
  }
}

// ---------------------------------------------------------------------------
// Main fused kernel
// ---------------------------------------------------------------------------
#define ESZ 444          // per-element scratch words (half-stride 888)
#define P5MT 272         // p5/aB mt-stride (halves)
#define P5K  544         // p5/aB k-stride
__global__ void __launch_bounds__(512)
ech_main(const float* __restrict__ sc, const float* __restrict__ t2s,
         float* __restrict__ out, int nGroups, CPack C) {
  __shared__ __align__(16) _Float16 slabh[SLABH];       // 29696 B
  __shared__ __align__(16) float scr[16 * ESZ];         // 28416 B
  __shared__ __align__(16) _Float16 unionH[5280];       // p5/aB(2720) + h2B(2560)
  __shared__ __align__(16) _Float16 cvvH[16 * 288];     // 9216 B
  __shared__ __align__(16) _Float16 h0st[16 * 40];      // 1280 B
  __shared__ __align__(16) _Float16 gst[16 * 40];       // 1280 B
  __shared__ int pairs9[48];
  __shared__ int sspair[68];

  const int tid  = threadIdx.x;
  const int lane = tid & 31;
  const int sub  = tid >> 5;
  const int w    = lane;

  _Float16* p5H  = unionH;           // [k][mt][e][16] (aB overlays, same strides)
  _Float16* h2Bb = unionH + 2720;    // [j][e][32]

  for (int i = tid; i < SLABH / 8; i += 512)
    ((float4*)slabh)[i] = ((const float4*)g_wsh)[i];
  if (tid < 45) { int u, v; tri_uv(tid, 9, u, v); pairs9[tid] = u | (v << 4); }
  if (tid < 68) {
    int u0, v0, u1, v1;
    tri_uv(2 * tid, 16, u0, v0);
    tri_uv(2 * tid + 1, 16, u1, v1);
    sspair[tid] = u0 | (v0 << 4) | (u1 << 8) | (v1 << 12);
  }

  constexpr int L2R[8] = {0, 1, 2, 4, 24, 26, 35, 38};

  // per-element scratch (words):
  float*     E    = scr + sub * ESZ;
  float*     Araw = E;                          // 0..199 (qBe overlays 0..159)
  _Float16*  qBe  = (_Float16*)E;               // [k<5][64] halves
  float*     tb   = E + 200;                    // [9][8] f32
  _Float16*  sshh = (_Float16*)(E + 272);       // 136 h  (sstt contiguous ->)
  _Float16*  tthh = (_Float16*)(E + 340);       // 56 h   (45 used + 11 pad)
  _Float16*  thh  = (_Float16*)(E + 368);       // [5][16] h
  float*     sL   = E + 408;                    // 16 f32
  int*       spad = (int*)(E + 424);            // 16 ints (32 halves)

  // one-time pad zeroing (regions never clobbered by staging)
  if (lane < 11)      tthh[45 + lane] = (_Float16)0.f;
  else if (lane < 16) thh[(lane - 11) * 16 + 9] = (_Float16)0.f;
  if (lane >= 24)     spad[lane - 16] = 0;

  // ---- prologue prefetch for first group ----
  float4 pf0 = {0.f, 0.f, 0.f, 0.f};
  float4 pf1 = {0.f, 0.f, 0.f, 0.f};
  float4 pfs = {0.f, 0.f, 0.f, 0.f};
  if (blockIdx.x < nGroups) {
    const int b0 = blockIdx.x * 16 + sub;
    const float4* src = (const float4*)(t2s + (size_t)b0 * 200);
    pf0 = src[lane];
    if (lane < 18) pf1 = src[lane + 32];
    if (lane < 4)  pfs = ((const float4*)(sc + (size_t)b0 * 16))[lane];
  }
  __syncthreads();

  for (int grp = blockIdx.x; grp < nGroups; grp += gridDim.x) {
    const int b = grp * 16 + sub;

    // ======== S1: per-element marshaling (from prefetched regs) ========
    {
      float4* Av = (float4*)Araw;
      Av[lane] = pf0;
      if (lane < 18) Av[lane + 32] = pf1;
      if (lane < 4) ((float4*)sL)[lane] = pfs;
    }
    // issue NEXT group's loads — consumed next iteration; they stay in
    // flight across the (vmcnt-preserving) in-loop barriers.
    {
      const int gnext = grp + gridDim.x;
      if (gnext < nGroups) {
        const int bn = gnext * 16 + sub;
        const float4* srcn = (const float4*)(t2s + (size_t)bn * 200);
        pf0 = srcn[lane];
        if (lane < 18) pf1 = srcn[lane + 32];
        if (lane < 4)  pfs = ((const float4*)(sc + (size_t)bn * 16))[lane];
      }
    }
    if (lane < 8) spad[lane] = h2i(pk2(sL[2 * lane], sL[2 * lane + 1]));

    // phase 1: t rows
    #pragma unroll
    for (int it = 0; it < 2; it++) {
      int idx = lane + 32 * it;
      if (idx < 40) {
        int r = idx / 5, c = idx % 5;
        float val = Araw[L2R[r] * 5 + c];
        tb[r * 8 + c] = val;
        thh[c * 16 + r] = (_Float16)val;
      }
    }
    { // kernel-sum row
      int l25 = lane % 25;
      int c2 = l25 / 5, j2 = l25 % 5;
      float acc = 0.f;
      #pragma unroll
      for (int rr = 0; rr < 8; rr++) acc += Araw[(j2 + 5 * rr) * 5 + c2];
      float tot = __shfl(acc, 5 * c2 + 0, 32) + __shfl(acc, 5 * c2 + 1, 32)
                + __shfl(acc, 5 * c2 + 2, 32) + __shfl(acc, 5 * c2 + 3, 32)
                + __shfl(acc, 5 * c2 + 4, 32);
      if (lane < 25 && j2 == 0) { tb[64 + c2] = tot; thh[c2 * 16 + 8] = (_Float16)tot; }
    }

    // phase 2: pairs -> tt + qB (overlays Araw; pads re-zeroed here)
    #pragma unroll
    for (int it = 0; it < 2; it++) {
      int idx = lane + 32 * it;
      if (idx < 45) {
        int pr = pairs9[idx];
        int pu = pr & 15, pv = pr >> 4;
        float4 u4 = *(const float4*)(tb + pu * 8); float u5 = tb[pu * 8 + 4];
        float4 v4 = *(const float4*)(tb + pv * 8); float v5 = tb[pv * 8 + 4];
        float tu[5] = {u4.x, u4.y, u4.z, u4.w, u5};
        float tv[5] = {v4.x, v4.y, v4.z, v4.w, v5};
        float tt = tu[0]*tv[0] + tu[1]*tv[1] + tu[2]*tv[2] + tu[3]*tv[3] + tu[4]*tv[4];
        tthh[idx] = (_Float16)tt;
        float qk[5] = {0, 0, 0, 0, 0};
        #pragma unroll
        for (int s = 0; s < 32; s++)
          qk[CKa[s]] = fmaf(C.v[s], tu[CIa[s]] * tv[CJa[s]], qk[CKa[s]]);
        #pragma unroll
        for (int k = 0; k < 5; k++) qBe[k * 64 + idx] = (_Float16)qk[k];
      } else {
        #pragma unroll
        for (int k = 0; k < 5; k++) qBe[k * 64 + idx] = (_Float16)0.f;
      }
    }

    // phase 3a: ss pair products
    #pragma unroll
    for (int ii = 0; ii < 3; ii++) {
      int slot = lane + 32 * ii;
      if (slot < 68) {
        int t = sspair[slot];
        int u0 = t & 15, v0 = (t >> 4) & 15, u1 = (t >> 8) & 15, v1 = (t >> 12) & 15;
        *(half2_t*)(sshh + 2 * slot) = pk2(sL[u0] * sL[v0], sL[u1] * sL[v1]);
      }
    }
    bar_lds();   // B1 (also cross-iteration fence)

    // ======== S2: MFMA stage 1 ========
    {
      const int wid = tid >> 6;
      const int L   = tid & 63;
      const int e2  = L & 15;
      const int q2  = L >> 4;
      const _Float16* scrH = (const _Float16*)scr;
      if (wid == 0) {
        // h0 only (g moved to S2b wave 5 — shortens this critical chain)
        f32x4_t a0 = {0.f, 0.f, 0.f, 0.f}, a1 = {0.f, 0.f, 0.f, 0.f};
        const _Float16* ssb = scrH + e2 * (2 * ESZ) + 544;
        #pragma unroll
        for (int ks = 0; ks < 6; ks++) {
          half8_t bb = *(const half8_t*)(ssb + ks * 32 + q2 * 8);
          a0 = mfma16(*(const half8_t*)(slabh + FW0 + ks * 512 + L * 8), bb, a0);
          a1 = mfma16(*(const half8_t*)(slabh + FW0 + (6 + ks) * 512 + L * 8), bb, a1);
        }
        store4h(h0st + e2 * 40 + q2 * 4, a0);
        store4h(h0st + e2 * 40 + 16 + q2 * 4, a1);
      } else if (wid <= 2) {
        // Cvv
        const _Float16* spb = scrH + e2 * (2 * ESZ) + 848;
        half8_t bb = *(const half8_t*)(spb + q2 * 8);
        const int t0 = (wid - 1) * 9;
        half8_t wz = {0, 0, 0, 0, 0, 0, 0, 0};
        #pragma unroll
        for (int t = 0; t < 9; t++) {
          half8_t wa = (q2 < 2) ? *(const half8_t*)(slabh + FWC + (t0 + t) * 256 + L * 8) : wz;
          f32x4_t z4 = {0.f, 0.f, 0.f, 0.f};
          f32x4_t d = mfma16(wa, bb, z4);
          store4h(cvvH + e2 * 288 + (t0 + t) * 16 + q2 * 4, d);
        }
      } else {
        // p5_k = W111 @ qT_k  (k = wid-3)
        const int k = wid - 3;
        const _Float16* qb = scrH + e2 * (2 * ESZ) + k * 64;
        f32x4_t d0 = {0.f, 0.f, 0.f, 0.f}, d1 = {0.f, 0.f, 0.f, 0.f};
        #pragma unroll
        for (int ks = 0; ks < 2; ks++) {
          half8_t bb = *(const half8_t*)(qb + ks * 32 + q2 * 8);
          d0 = mfma16(*(const half8_t*)(slabh + FW111 + ks * 512 + L * 8), bb, d0);
          d1 = mfma16(*(const half8_t*)(slabh + FW111 + (2 + ks) * 512 + L * 8), bb, d1);
        }
        store4h(p5H + k * P5K + e2 * 16 + q2 * 4, d0);
        store4h(p5H + k * P5K + P5MT + e2 * 16 + q2 * 4, d1);
      }
    }
    bar_lds();   // B2

    // ======== S3a: h2 = Cvv.t + p5; write h2B ========
    float Cvv[9];
    #pragma unroll
    for (int v = 0; v < 9; v++) Cvv[v] = (float)cvvH[sub * 288 + w * 9 + v];
    half2_t cpk[5] = { pk2(Cvv[0], Cvv[1]), pk2(Cvv[2], Cvv[3]),
                       pk2(Cvv[4], Cvv[5]), pk2(Cvv[6], Cvv[7]), pk2(Cvv[8], 0.f) };
    float h2r[5];
    #pragma unroll
    for (int k = 0; k < 5; k++) {
      H8 d; d.v = *(const half8_t*)(thh + k * 16);
      half2_t d4 = *(const half2_t*)(thh + k * 16 + 8);
      float acc = dot2f(cpk[0], d.p[0], 0.f);
      acc = dot2f(cpk[1], d.p[1], acc);
      acc = dot2f(cpk[2], d.p[2], acc);
      acc = dot2f(cpk[3], d.p[3], acc);
      acc = dot2f(cpk[4], d4, acc);
      h2r[k] = acc + (float)p5H[k * P5K + (w >> 4) * P5MT + sub * 16 + (w & 15)];
    }
    #pragma unroll
    for (int k = 0; k < 5; k++) h2Bb[k * 512 + sub * 32 + w] = (_Float16)h2r[k];
    bar_lds();   // B3

    // ======== S2b: aB_j = V110 @ h2_j (waves 0-4); g = Mr @ h0 (wave 5) ====
    {
      const int wid = tid >> 6;
      const int L   = tid & 63;
      const int e2  = L & 15;
      const int q2  = L >> 4;
      if (wid < 5) {
        const int j = wid;
        half8_t bb = *(const half8_t*)(h2Bb + j * 512 + e2 * 32 + q2 * 8);
        f32x4_t z4 = {0.f, 0.f, 0.f, 0.f};
        f32x4_t d0 = mfma16(*(const half8_t*)(slabh + FV110 + L * 8), bb, z4);
        f32x4_t d1 = mfma16(*(const half8_t*)(slabh + FV110 + 512 + L * 8), bb, z4);
        store4h(p5H + j * P5K + e2 * 16 + q2 * 4, d0);          // aB overlays p5
        store4h(p5H + j * P5K + P5MT + e2 * 16 + q2 * 4, d1);
      } else if (wid == 5) {
        // g = Mr @ h0 (h0st written pre-B2 by wave 0; consumed post-B4 in S3c)
        half8_t hb = *(const half8_t*)(h0st + e2 * 40 + q2 * 8);
        f32x4_t z4 = {0.f, 0.f, 0.f, 0.f};
        f32x4_t g0 = mfma16(*(const half8_t*)(slabh + FMR + L * 8), hb, z4);
        f32x4_t g1 = mfma16(*(const half8_t*)(slabh + FMR + 512 + L * 8), hb, z4);
        store4h(gst + e2 * 40 + q2 * 4, g0);
        store4h(gst + e2 * 40 + 16 + q2 * 4, g1);
      }
    }
    bar_lds();   // B4

    // ======== S3c: final ========
    float a5[5];
    #pragma unroll
    for (int j = 0; j < 5; j++)
      a5[j] = (float)p5H[j * P5K + (w >> 4) * P5MT + sub * 16 + (w & 15)];
    float g = (float)gst[sub * 40 + w];

    float yv[5] = {0, 0, 0, 0, 0};
    #pragma unroll
    for (int s = 0; s < 32; s++)
      yv[CKa[s]] = fmaf(C.v[s], h2r[CIa[s]] * a5[CJa[s]], yv[CKa[s]]);

    const float DCONST = sqrtf(5.0f / 3072.0f);
    float z[5];
    #pragma unroll
    for (int k = 0; k < 5; k++) z[k] = fmaf(DCONST, yv[k], g * h2r[k]);

    half2_t z01 = pk2(z[0], z[1]);
    half2_t z23 = pk2(z[2], z[3]);
    float   z4r = z[4];
    #pragma unroll
    for (int st = 1; st <= 16; st <<= 1) {
      z01 = z01 + i2h(__shfl_xor(h2i(z01), st));
      z23 = z23 + i2h(__shfl_xor(h2i(z23), st));
      z4r += __shfl_xor(z4r, st);
    }
    if (lane < 5) {
      float val = (lane == 0) ? (float)z01[0]
                : (lane == 1) ? (float)z01[1]
                : (lane == 2) ? (float)z23[0]
                : (lane == 3) ? (float)z23[1] : z4r;
      out[(size_t)b * 5 + lane] = val;
    }
  }
}

// ---------------------------------------------------------------------------
extern "C" void kernel_launch(void* const* d_in, const int* in_sizes, int n_in,
                              void* d_out, int out_size, void* d_ws, size_t ws_size,
                              hipStream_t stream) {
  (void)n_in; (void)out_size; (void)d_ws; (void)ws_size;

  CPack C;
  computeC(C);

  ech_setup<<<64, 256, 0, stream>>>(
      (const float*)d_in[2], (const float*)d_in[3], (const float*)d_in[4],
      (const float*)d_in[5], (const float*)d_in[6], (const float*)d_in[7],
      (const float*)d_in[8], (const float*)d_in[9]);

  const int B = in_sizes[0] / 16;
  const int nGroups = B / 16;
  ech_main<<<512, 512, 0, stream>>>(
      (const float*)d_in[0], (const float*)d_in[1], (float*)d_out, nGroups, C);
}